// Round 4
// baseline (2483.895 us; speedup 1.0000x reference)
//
#include <hip/hip_runtime.h>
#include <hip/hip_bf16.h>
#include <stdint.h>

// ---------------------------------------------------------------------------
// Decoder_64905545777804 — fp32 I/O, bf16-MFMA internals.
// B=16, LAT=512, NF=32, IMG=128 (16384 px), NC=12
// R2 changes vs R1 (2331 us):
//  - k_gwrite DELETED: k_conv computes sobel+inorm of prev inline into LDS
//    (XH buffer time-shared between X g-half and H1/H2; extra sync added
//    between layer-1 X reads and H1 writes). Saves 33.5MB write + 67MB read
//    + one dispatch per iteration.
//  - xin now holds only the static wave half: [b][px][64] bf16 (33.5 MB).
//  - k_wavewrite writes the 64-ch rows directly.
// R1 (kept): embs-chained scan state, skip-GEMM fused into layer-1,
//  XCD-aware wavegemm remap, single-pass wavestats, it=0 gstats skip.
// ---------------------------------------------------------------------------

typedef __attribute__((ext_vector_type(8))) short s8v;   // 8 x bf16 (4 VGPRs)
typedef __attribute__((ext_vector_type(4))) float f4v;   // 4 x fp32

__device__ __forceinline__ uint16_t f2b(float f) {
    uint32_t x = __builtin_bit_cast(uint32_t, f);
    uint32_t r = (x + 0x7fffu + ((x >> 16) & 1u)) >> 16;   // RNE
    return (uint16_t)r;
}

__device__ __forceinline__ float blockReduceSum(float v, float* scratch) {
    #pragma unroll
    for (int o = 32; o > 0; o >>= 1) v += __shfl_down(v, o, 64);
    int w = threadIdx.x >> 6;
    if ((threadIdx.x & 63) == 0) scratch[w] = v;
    __syncthreads();
    float r = scratch[0] + scratch[1] + scratch[2] + scratch[3];
    __syncthreads();
    return r;
}

// ---- K1: h_wt = relu(lat@wt_w1+b1) [16x512], h_c2c = relu(lat@c2c_w1+b1) [16x1024]
// outputs stored TRANSPOSED: hT[j][b].
__global__ __launch_bounds__(256) void k_hyper1(const float* __restrict__ lat,
        const float* __restrict__ w1a, const float* __restrict__ b1a,
        const float* __restrict__ w1b, const float* __restrict__ b1b,
        float* __restrict__ hwtT, float* __restrict__ hc2cT) {
    int b = blockIdx.y;
    int j = blockIdx.x * 256 + threadIdx.x;
    __shared__ float lats[512];
    for (int k = threadIdx.x; k < 512; k += 256) lats[k] = lat[b * 512 + k];
    __syncthreads();
    if (j < 512) {
        float acc = b1a[j];
        #pragma unroll 4
        for (int k = 0; k < 512; k++) acc += lats[k] * w1a[k * 512 + j];
        hwtT[j * 16 + b] = fmaxf(acc, 0.f);
    } else {
        int jj = j - 512;
        float acc = b1b[jj];
        #pragma unroll 4
        for (int k = 0; k < 512; k++) acc += lats[k] * w1b[k * 1024 + jj];
        hc2cT[jj * 16 + b] = fmaxf(acc, 0.f);
    }
}

// ---- K2: p = hT^T @ w2 + b2  (streams w2; one column per thread, 16 batches)
__global__ __launch_bounds__(256) void k_hyper2(const float* __restrict__ hT,
        const float* __restrict__ w2, const float* __restrict__ b2v,
        float* __restrict__ outp, int K, int N) {
    extern __shared__ float hs[];     // [K][16]
    for (int i = threadIdx.x; i < K * 16; i += 256) hs[i] = hT[i];
    __syncthreads();
    int col = blockIdx.x * 256 + threadIdx.x;
    if (col >= N) return;
    float acc[16];
    float bias = b2v[col];
    #pragma unroll
    for (int b = 0; b < 16; b++) acc[b] = bias;
    #pragma unroll 4
    for (int k = 0; k < K; k++) {
        float wv = w2[(size_t)k * N + col];
        const f4v* h4 = (const f4v*)(hs + k * 16);
        f4v h0 = h4[0], h1 = h4[1], h2 = h4[2], h3 = h4[3];
        acc[0]  += h0[0] * wv; acc[1]  += h0[1] * wv; acc[2]  += h0[2] * wv; acc[3]  += h0[3] * wv;
        acc[4]  += h1[0] * wv; acc[5]  += h1[1] * wv; acc[6]  += h1[2] * wv; acc[7]  += h1[3] * wv;
        acc[8]  += h2[0] * wv; acc[9]  += h2[1] * wv; acc[10] += h2[2] * wv; acc[11] += h2[3] * wv;
        acc[12] += h3[0] * wv; acc[13] += h3[1] * wv; acc[14] += h3[2] * wv; acc[15] += h3[3] * wv;
    }
    #pragma unroll
    for (int b = 0; b < 16; b++) outp[(size_t)b * N + col] = acc[b];
}

// ---- K2b: pre-scale dynamic weights to bf16.
__global__ __launch_bounds__(256) void k_prepw(const float* __restrict__ pw, const float* __restrict__ pc,
        uint16_t* __restrict__ ww, uint16_t* __restrict__ wc) {
    int tid = blockIdx.x * 256 + threadIdx.x;
    const float s128 = 0.08838834764831845f;
    const float s64  = 0.125f;
    const float s2048 = 0.02209708691207961f;
    if (tid < 16 * 65536) {
        int b = tid >> 16, r = tid & 65535;
        ww[tid] = f2b(pw[(size_t)b * 65568 + r] * s2048);
    } else {
        int t = tid - 16 * 65536;
        int b = t / 24576, r = t % 24576;
        int src; float sc;
        if (r < 8192)       { src = r;                   sc = s128; }
        else if (r < 12288) { src = 8256  + (r - 8192);  sc = s64; }
        else if (r < 16384) { src = 12416 + (r - 12288); sc = s64; }
        else                { src = 16576 + (r - 16384); sc = s128; }
        wc[(size_t)b * 24576 + r] = f2b(pc[(size_t)b * 24832 + src] * sc);
    }
}

// ---- transpose + bf16-convert wave_bias [2048][16384] -> wbt [16384][2048]
__global__ __launch_bounds__(256) void k_transpose(const float* __restrict__ wb, uint16_t* __restrict__ wbt) {
    __shared__ uint16_t tile[64][66];
    int p0 = blockIdx.x * 64, i0 = blockIdx.y * 64;
    int lane = threadIdx.x & 63, grp = threadIdx.x >> 6;
    #pragma unroll
    for (int r = 0; r < 16; r++) {
        int i = grp * 16 + r;
        tile[i][lane] = f2b(wb[(size_t)(i0 + i) * 16384 + p0 + lane]);
    }
    __syncthreads();
    #pragma unroll
    for (int r = 0; r < 16; r++) {
        int p = grp * 16 + r;
        wbt[(size_t)(p0 + p) * 2048 + i0 + lane] = tile[lane][p];
    }
}

// ---- K3: wb[m=(b,o)][px] = sum_i ww[m][i]*wbt[px][i] + wbb[b][o]   M=512,N=16384,K=2048
__global__ __launch_bounds__(256) void k_wavegemm(const uint16_t* __restrict__ ww,
        const uint16_t* __restrict__ wbt, const float* __restrict__ pw, float* __restrict__ wb) {
    int id = blockIdx.x;                 // 0..511
    int xcd = id & 7, slot = id >> 3;    // slot 0..63 on this XCD
    int nt = xcd * 8 + (slot >> 3);      // 64 tiles of 256 px
    int mt = slot & 7;                   // 8 tiles of 64 rows
    int w = threadIdx.x >> 6, L = threadIdx.x & 63;
    int l15 = L & 15, quad = L >> 4;
    int pxbase = nt * 256 + w * 64;
    f4v acc[4][4];
    #pragma unroll
    for (int t = 0; t < 4; t++) {
        int m = mt * 64 + t * 16 + quad * 4;
        int b = m >> 5, o = m & 31;
        f4v bv = *(const f4v*)(pw + (size_t)b * 65568 + 65536 + o);
        #pragma unroll
        for (int j = 0; j < 4; j++) acc[t][j] = bv;
    }
    #pragma unroll 2
    for (int kk = 0; kk < 64; kk++) {
        s8v a[4], x[4];
        #pragma unroll
        for (int t = 0; t < 4; t++) {
            int m = mt * 64 + t * 16 + l15;
            a[t] = *(const s8v*)(ww + (size_t)m * 2048 + kk * 32 + quad * 8);
        }
        #pragma unroll
        for (int j = 0; j < 4; j++) {
            int p = pxbase + j * 16 + l15;
            x[j] = *(const s8v*)(wbt + (size_t)p * 2048 + kk * 32 + quad * 8);
        }
        #pragma unroll
        for (int t = 0; t < 4; t++)
            #pragma unroll
            for (int j = 0; j < 4; j++)
                acc[t][j] = __builtin_amdgcn_mfma_f32_16x16x32_bf16(a[t], x[j], acc[t][j], 0, 0, 0);
    }
    #pragma unroll
    for (int t = 0; t < 4; t++)
        #pragma unroll
        for (int j = 0; j < 4; j++)
            #pragma unroll
            for (int r = 0; r < 4; r++) {
                int row = mt * 64 + t * 16 + quad * 4 + r;
                int p = pxbase + j * 16 + l15;
                wb[(size_t)row * 16384 + p] = acc[t][j][r];
            }
}

// ---- K4a: per (b, channel c<32) inorm stats for BOTH cos (c) and sin (c+32),
// single pass over wb (var = E[x^2]-m^2).
__global__ __launch_bounds__(256) void k_wavestats(const float* __restrict__ wb, float* __restrict__ stats) {
    __shared__ float scratch[4];
    int c = blockIdx.x, b = blockIdx.y;          // c in 0..31
    const float* src = wb + (size_t)(b * 32 + c) * 16384;
    float sc = 0.f, sc2 = 0.f, ss = 0.f, ss2 = 0.f;
    for (int p = threadIdx.x; p < 16384; p += 256) {
        float x = src[p];
        float cv = __cosf(x), sv = __sinf(x);
        sc += cv; sc2 += cv * cv; ss += sv; ss2 += sv * sv;
    }
    float SC  = blockReduceSum(sc,  scratch);
    float SC2 = blockReduceSum(sc2, scratch);
    float SS  = blockReduceSum(ss,  scratch);
    float SS2 = blockReduceSum(ss2, scratch);
    if (threadIdx.x == 0) {
        float mc = SC * (1.f / 16384.f);
        float vc = fmaxf(SC2 * (1.f / 16384.f) - mc * mc, 0.f);
        float ms = SS * (1.f / 16384.f);
        float vs = fmaxf(SS2 * (1.f / 16384.f) - ms * ms, 0.f);
        stats[(b * 64 + c) * 2 + 0] = mc;
        stats[(b * 64 + c) * 2 + 1] = rsqrtf(vc + 1e-5f);
        stats[(b * 64 + 32 + c) * 2 + 0] = ms;
        stats[(b * 64 + 32 + c) * 2 + 1] = rsqrtf(vs + 1e-5f);
    }
}

// ---- K4b: write normalized wave into XINW[b][px][64] (pixel-major, bf16)
// one wb read yields both cos (c) and sin (c+32) channels.
__global__ __launch_bounds__(256) void k_wavewrite(const float* __restrict__ wb,
        const float* __restrict__ stats, uint16_t* __restrict__ xinw) {
    __shared__ uint16_t tl[256][66];
    __shared__ float sst[128];
    int b = blockIdx.y, p0 = blockIdx.x * 256;
    int t = threadIdx.x;
    if (t < 128) sst[t] = stats[b * 128 + t];
    __syncthreads();
    for (int c = 0; c < 32; c++) {
        int row = b * 32 + c;
        float x = wb[(size_t)row * 16384 + p0 + t];
        float cv = __cosf(x), sv = __sinf(x);
        tl[t][c]      = f2b((cv - sst[2 * c]) * sst[2 * c + 1]);
        tl[t][c + 32] = f2b((sv - sst[64 + 2 * c]) * sst[64 + 2 * c + 1]);
    }
    __syncthreads();
    uint16_t* dst = xinw + (size_t)(b * 16384 + p0 + t) * 64;
    const uint32_t* s32 = (const uint32_t*)&tl[t][0];
    #pragma unroll
    for (int c8 = 0; c8 < 64; c8 += 8) {
        uint4 v;
        v.x = s32[c8 / 2 + 0]; v.y = s32[c8 / 2 + 1];
        v.z = s32[c8 / 2 + 2]; v.w = s32[c8 / 2 + 3];
        *(uint4*)(dst + c8) = v;
    }
}

// ---- K5a: per-iteration sobel stats. block=(ic,b): channels 2ic (ky), 2ic+1 (kx)
__global__ __launch_bounds__(256) void k_gstats(const float* __restrict__ prev, float* __restrict__ stats) {
    __shared__ float scratch[4];
    int ic = blockIdx.x, b = blockIdx.y;
    const float* src = prev + (size_t)(b * 32 + ic) * 16384;
    float sy = 0.f, sy2 = 0.f, sx = 0.f, sx2 = 0.f;
    for (int p = threadIdx.x; p < 16384; p += 256) {
        int y = p >> 7, x = p & 127;
        float up = (y > 0)   ? src[p - 128] : 0.f;
        float dn = (y < 127) ? src[p + 128] : 0.f;
        float lf = (x > 0)   ? src[p - 1]   : 0.f;
        float rt = (x < 127) ? src[p + 1]   : 0.f;
        float vy = dn - up, vx = rt - lf;
        sy += vy; sy2 += vy * vy; sx += vx; sx2 += vx * vx;
    }
    float SY  = blockReduceSum(sy,  scratch);
    float SY2 = blockReduceSum(sy2, scratch);
    float SX  = blockReduceSum(sx,  scratch);
    float SX2 = blockReduceSum(sx2, scratch);
    if (threadIdx.x == 0) {
        float my = SY * (1.f / 16384.f);
        float vy = fmaxf(SY2 * (1.f / 16384.f) - my * my, 0.f);
        float mx = SX * (1.f / 16384.f);
        float vx = fmaxf(SX2 * (1.f / 16384.f) - mx * mx, 0.f);
        stats[(b * 64 + 2 * ic) * 2 + 0] = my;
        stats[(b * 64 + 2 * ic) * 2 + 1] = rsqrtf(vy + 1e-5f);
        stats[(b * 64 + 2 * ic + 1) * 2 + 0] = mx;
        stats[(b * 64 + 2 * ic + 1) * 2 + 1] = rsqrtf(vx + 1e-5f);
    }
}

// ---- K6: fused conv chain, one scan step. Sobel+inorm computed inline into
// LDS (was k_gwrite); XH buffer time-shared between X g-half and H1/H2.
// Skip-GEMM fused into layer-1. State chained through embs slices.
__global__ __launch_bounds__(256) void k_conv(const uint16_t* __restrict__ wc,
        const uint16_t* __restrict__ xinw, const float* __restrict__ pc,
        const float* __restrict__ statg,
        const float* __restrict__ prev, float* __restrict__ next,
        const float* __restrict__ leakp) {
    __shared__ uint16_t XH[256][72];           // [px][ch] — X(g) then H1 then H2
    int b = blockIdx.y, p0 = blockIdx.x * 256;
    int t = threadIdx.x;
    int w = t >> 6, L = t & 63;
    int l15 = L & 15, quad = L >> 4;
    const uint16_t* wcb = wc + (size_t)b * 24576;
    const float* pcb = pc + (size_t)b * 24832;

    // ---- phase 0: g = inorm(sobel(prev)) for this block's 256 px -> XH[t][0..63]
    {
        int p = p0 + t;
        int y = p >> 7, x = p & 127;
        for (int ic = 0; ic < 32; ic++) {
            const float* src = prev + (size_t)(b * 32 + ic) * 16384;
            float up = (y > 0)   ? src[p - 128] : 0.f;
            float dn = (y < 127) ? src[p + 128] : 0.f;
            float lf = (x > 0)   ? src[p - 1]   : 0.f;
            float rt = (x < 127) ? src[p + 1]   : 0.f;
            int o = 2 * ic;
            float m0 = statg[(b * 64 + o) * 2],     r0 = statg[(b * 64 + o) * 2 + 1];
            float m1 = statg[(b * 64 + o + 1) * 2], r1 = statg[(b * 64 + o + 1) * 2 + 1];
            uint32_t u = (uint32_t)f2b((dn - up - m0) * r0)
                       | ((uint32_t)f2b((rt - lf - m1) * r1) << 16);
            *(uint32_t*)&XH[t][o] = u;
        }
    }
    __syncthreads();

    size_t xwbase = ((size_t)b * 16384 + p0 + w * 64) * 64;

    // ---- layer 1 + skip: acc1 = Win@X + b_in; acc3 = Wsk@X + (b_out+b_sk)
    // X channels 0..63 from XH (LDS), 64..127 from global wave buffer.
    f4v acc1[4][4], acc3[4][4];
    #pragma unroll
    for (int tt = 0; tt < 4; tt++) {
        f4v bv1 = *(const f4v*)(pcb + 8192 + tt * 16 + quad * 4);
        f4v bo  = *(const f4v*)(pcb + 16512 + tt * 16 + quad * 4);
        f4v bs  = *(const f4v*)(pcb + 24768 + tt * 16 + quad * 4);
        f4v bv3 = bo + bs;
        #pragma unroll
        for (int j = 0; j < 4; j++) { acc1[tt][j] = bv1; acc3[tt][j] = bv3; }
    }
    #pragma unroll
    for (int kk = 0; kk < 4; kk++) {
        s8v x[4];
        #pragma unroll
        for (int j = 0; j < 4; j++) {
            int px = w * 64 + j * 16 + l15;
            if (kk < 2)
                x[j] = *(const s8v*)&XH[px][kk * 32 + quad * 8];
            else
                x[j] = *(const s8v*)(xinw + xwbase + (size_t)(j * 16 + l15) * 64
                                     + (kk - 2) * 32 + quad * 8);
        }
        #pragma unroll
        for (int tt = 0; tt < 4; tt++) {
            s8v a1 = *(const s8v*)(wcb + (size_t)(tt * 16 + l15) * 128 + kk * 32 + quad * 8);
            #pragma unroll
            for (int j = 0; j < 4; j++)
                acc1[tt][j] = __builtin_amdgcn_mfma_f32_16x16x32_bf16(a1, x[j], acc1[tt][j], 0, 0, 0);
        }
        #pragma unroll
        for (int tt = 0; tt < 4; tt++) {
            s8v a3 = *(const s8v*)(wcb + 16384 + (size_t)(tt * 16 + l15) * 128 + kk * 32 + quad * 8);
            #pragma unroll
            for (int j = 0; j < 4; j++)
                acc3[tt][j] = __builtin_amdgcn_mfma_f32_16x16x32_bf16(a3, x[j], acc3[tt][j], 0, 0, 0);
        }
    }
    __syncthreads();    // all XH (X) reads complete before overwriting with H1

    #pragma unroll
    for (int tt = 0; tt < 4; tt++)
        #pragma unroll
        for (int j = 0; j < 4; j++) {
            uint16_t pk[4];
            #pragma unroll
            for (int r = 0; r < 4; r++) {
                float v = acc1[tt][j][r];
                pk[r] = f2b(v > 0.f ? v : 0.2f * v);
            }
            int px = w * 64 + j * 16 + l15;
            int ch = tt * 16 + quad * 4;
            uint2 u; u.x = (uint32_t)pk[0] | ((uint32_t)pk[1] << 16);
            u.y = (uint32_t)pk[2] | ((uint32_t)pk[3] << 16);
            *(uint2*)&XH[px][ch] = u;       // H1
        }
    __syncthreads();

    // ---- layer 2: H2 = lrelu(Wmid @ H1 + b_mid)
    f4v acc2[4][4];
    #pragma unroll
    for (int tt = 0; tt < 4; tt++) {
        f4v bv = *(const f4v*)(pcb + 12352 + tt * 16 + quad * 4);
        #pragma unroll
        for (int j = 0; j < 4; j++) acc2[tt][j] = bv;
    }
    #pragma unroll
    for (int kk = 0; kk < 2; kk++) {
        s8v a[4], h[4];
        #pragma unroll
        for (int tt = 0; tt < 4; tt++)
            a[tt] = *(const s8v*)(wcb + 8192 + (size_t)(tt * 16 + l15) * 64 + kk * 32 + quad * 8);
        #pragma unroll
        for (int j = 0; j < 4; j++) {
            int px = w * 64 + j * 16 + l15;
            h[j] = *(const s8v*)&XH[px][kk * 32 + quad * 8];
        }
        #pragma unroll
        for (int tt = 0; tt < 4; tt++)
            #pragma unroll
            for (int j = 0; j < 4; j++)
                acc2[tt][j] = __builtin_amdgcn_mfma_f32_16x16x32_bf16(a[tt], h[j], acc2[tt][j], 0, 0, 0);
    }
    __syncthreads();
    #pragma unroll
    for (int tt = 0; tt < 4; tt++)
        #pragma unroll
        for (int j = 0; j < 4; j++) {
            uint16_t pk[4];
            #pragma unroll
            for (int r = 0; r < 4; r++) {
                float v = acc2[tt][j][r];
                pk[r] = f2b(v > 0.f ? v : 0.2f * v);
            }
            int px = w * 64 + j * 16 + l15;
            int ch = tt * 16 + quad * 4;
            uint2 u; u.x = (uint32_t)pk[0] | ((uint32_t)pk[1] << 16);
            u.y = (uint32_t)pk[2] | ((uint32_t)pk[3] << 16);
            *(uint2*)&XH[px][ch] = u;       // H2
        }
    __syncthreads();

    // ---- layer 3 (mid part): acc3 += Wout @ H2
    #pragma unroll
    for (int kk = 0; kk < 2; kk++) {
        s8v a[4], h[4];
        #pragma unroll
        for (int tt = 0; tt < 4; tt++)
            a[tt] = *(const s8v*)(wcb + 12288 + (size_t)(tt * 16 + l15) * 64 + kk * 32 + quad * 8);
        #pragma unroll
        for (int j = 0; j < 4; j++) {
            int px = w * 64 + j * 16 + l15;
            h[j] = *(const s8v*)&XH[px][kk * 32 + quad * 8];
        }
        #pragma unroll
        for (int tt = 0; tt < 4; tt++)
            #pragma unroll
            for (int j = 0; j < 4; j++)
                acc3[tt][j] = __builtin_amdgcn_mfma_f32_16x16x32_bf16(a[tt], h[j], acc3[tt][j], 0, 0, 0);
    }

    // ---- epilogue: GLU gate + leaky integrate into NEXT embs slice.
    float leak = leakp[0];
    leak = fminf(fmaxf(leak, 0.001f), 1000.f);
    #pragma unroll
    for (int tt = 0; tt < 2; tt++)
        #pragma unroll
        for (int j = 0; j < 4; j++) {
            int px = p0 + w * 64 + j * 16 + l15;
            #pragma unroll
            for (int r = 0; r < 4; r++) {
                int ch = tt * 16 + quad * 4 + r;
                float y1 = acc3[tt][j][r];
                float y2 = acc3[tt + 2][j][r];
                float on = y1 / (1.f + __expf(-y2));
                size_t idx = (size_t)(b * 32 + ch) * 16384 + px;
                next[idx] = prev[idx] + leak * on;
            }
        }
}

// ---- K7: out_raw = out @ out_w^T + out_b; clip -> d_out[0], raw -> d_out[2]
__global__ __launch_bounds__(256) void k_final(const float* __restrict__ outs,
        const float* __restrict__ ow, const float* __restrict__ ob,
        float* __restrict__ dclip, float* __restrict__ draw) {
    __shared__ float ws[3][32];
    __shared__ float obs[3];
    int b = blockIdx.y, p0 = blockIdx.x * 256;
    int t = threadIdx.x;
    if (t < 96) ws[t / 32][t % 32] = ow[t];
    if (t < 3) obs[t] = ob[t];
    __syncthreads();
    int p = p0 + t;
    float a0 = obs[0], a1 = obs[1], a2 = obs[2];
    #pragma unroll 4
    for (int c = 0; c < 32; c++) {
        float v = outs[(size_t)(b * 32 + c) * 16384 + p];
        a0 += v * ws[0][c]; a1 += v * ws[1][c]; a2 += v * ws[2][c];
    }
    float raw[3] = {a0, a1, a2};
    #pragma unroll
    for (int oc = 0; oc < 3; oc++) {
        size_t idx = (size_t)(b * 3 + oc) * 16384 + p;
        draw[idx] = raw[oc];
        dclip[idx] = fminf(fmaxf(raw[oc], -1.f), 1.f);
    }
}

// ---------------------------------------------------------------------------
extern "C" void kernel_launch(void* const* d_in, const int* in_sizes, int n_in,
                              void* d_out, int out_size, void* d_ws, size_t ws_size,
                              hipStream_t stream) {
    const float* lat   = (const float*)d_in[0];
    const float* leakp = (const float*)d_in[1];
    const float* wbias = (const float*)d_in[2];
    const float* wtw1  = (const float*)d_in[3];
    const float* wtb1  = (const float*)d_in[4];
    const float* wtw2  = (const float*)d_in[5];
    const float* wtb2  = (const float*)d_in[6];
    const float* cw1   = (const float*)d_in[7];
    const float* cb1   = (const float*)d_in[8];
    const float* cw2   = (const float*)d_in[9];
    const float* cb2   = (const float*)d_in[10];
    const float* outw  = (const float*)d_in[11];
    const float* outb  = (const float*)d_in[12];
    float* out_f = (float*)d_out;

    char* ws = (char*)d_ws;
    float*    hwtT  = (float*)(ws + 0);            //  32768 B
    float*    hc2cT = (float*)(ws + 32768);        //  65536 B
    float*    pw    = (float*)(ws + 98304);        //  16x65568 f32
    float*    pc    = (float*)(ws + 4294656);      //  16x24832 f32
    uint16_t* ww    = (uint16_t*)(ws + 5883904);   //  512x2048 bf16
    uint16_t* wc    = (uint16_t*)(ws + 7981056);   //  16x24576 bf16
    float*    statw = (float*)(ws + 8767488);      //  16x64x2 f32
    float*    statg = (float*)(ws + 8775680);      //  16x64x2 f32
    float*    wb    = (float*)(ws + 8783872);      //  512x16384 f32
    uint16_t* wbt   = (uint16_t*)(ws + 42338304);  //  16384x2048 bf16
    uint16_t* xinw  = (uint16_t*)(ws + 109447168); //  16x16384x64 bf16 (wave half)

    float* emb0 = out_f + 786432;                  // embs[0] slice (= scan state 0)

    hipMemsetAsync(emb0, 0, 33554432, stream);     // embs[0] = out0 = 0
    hipMemsetAsync(statg, 0, 8192, stream);        // it=0 stats (sobel of 0 is 0)

    k_hyper1<<<dim3(6, 16), 256, 0, stream>>>(lat, wtw1, wtb1, cw1, cb1, hwtT, hc2cT);
    k_hyper2<<<dim3(257), 256, 32768, stream>>>(hwtT, wtw2, wtb2, pw, 512, 65568);
    k_hyper2<<<dim3(97), 256, 65536, stream>>>(hc2cT, cw2, cb2, pc, 1024, 24832);
    k_prepw<<<dim3(5632), 256, 0, stream>>>(pw, pc, ww, wc);
    k_transpose<<<dim3(256, 32), 256, 0, stream>>>(wbias, wbt);
    k_wavegemm<<<dim3(512), 256, 0, stream>>>(ww, wbt, pw, wb);
    k_wavestats<<<dim3(32, 16), 256, 0, stream>>>(wb, statw);
    k_wavewrite<<<dim3(64, 16), 256, 0, stream>>>(wb, statw, xinw);

    for (int it = 0; it < 12; ++it) {
        const float* prev = emb0 + (size_t)it * 8388608;
        float* next = emb0 + (size_t)(it + 1) * 8388608;
        if (it > 0)
            k_gstats<<<dim3(32, 16), 256, 0, stream>>>(prev, statg);
        k_conv<<<dim3(64, 16), 256, 0, stream>>>(wc, xinw, pc, statg, prev, next, leakp);
    }
    k_final<<<dim3(64, 16), 256, 0, stream>>>(emb0 + (size_t)12 * 8388608, outw, outb,
                                              out_f, out_f + 109838336);
}

// Round 5
// 2151.236 us; speedup vs baseline: 1.1546x; 1.1546x over previous
//
#include <hip/hip_runtime.h>
#include <hip/hip_bf16.h>
#include <stdint.h>

// ---------------------------------------------------------------------------
// Decoder_64905545777804 — fp32 I/O, bf16-MFMA internals.
// B=16, LAT=512, NF=32, IMG=128 (16384 px), NC=12
// R3 = R1 structure (2331 us; R2's sobel-in-conv fusion regressed to 2484 and
// is reverted) + float4-vectorized k_gstats (256 scalar loads/thread -> ~56
// wide loads/thread, all 16B-coalesced, wave-uniform branches).
// R1 (kept): embs-chained scan state, skip-GEMM fused into layer-1,
//  XCD-aware wavegemm remap, single-pass wavestats, it=0 gstats skip.
// ---------------------------------------------------------------------------

typedef __attribute__((ext_vector_type(8))) short s8v;   // 8 x bf16 (4 VGPRs)
typedef __attribute__((ext_vector_type(4))) float f4v;   // 4 x fp32

__device__ __forceinline__ uint16_t f2b(float f) {
    uint32_t x = __builtin_bit_cast(uint32_t, f);
    uint32_t r = (x + 0x7fffu + ((x >> 16) & 1u)) >> 16;   // RNE
    return (uint16_t)r;
}

__device__ __forceinline__ float blockReduceSum(float v, float* scratch) {
    #pragma unroll
    for (int o = 32; o > 0; o >>= 1) v += __shfl_down(v, o, 64);
    int w = threadIdx.x >> 6;
    if ((threadIdx.x & 63) == 0) scratch[w] = v;
    __syncthreads();
    float r = scratch[0] + scratch[1] + scratch[2] + scratch[3];
    __syncthreads();
    return r;
}

// ---- K1: h_wt = relu(lat@wt_w1+b1) [16x512], h_c2c = relu(lat@c2c_w1+b1) [16x1024]
// outputs stored TRANSPOSED: hT[j][b].
__global__ __launch_bounds__(256) void k_hyper1(const float* __restrict__ lat,
        const float* __restrict__ w1a, const float* __restrict__ b1a,
        const float* __restrict__ w1b, const float* __restrict__ b1b,
        float* __restrict__ hwtT, float* __restrict__ hc2cT) {
    int b = blockIdx.y;
    int j = blockIdx.x * 256 + threadIdx.x;
    __shared__ float lats[512];
    for (int k = threadIdx.x; k < 512; k += 256) lats[k] = lat[b * 512 + k];
    __syncthreads();
    if (j < 512) {
        float acc = b1a[j];
        #pragma unroll 4
        for (int k = 0; k < 512; k++) acc += lats[k] * w1a[k * 512 + j];
        hwtT[j * 16 + b] = fmaxf(acc, 0.f);
    } else {
        int jj = j - 512;
        float acc = b1b[jj];
        #pragma unroll 4
        for (int k = 0; k < 512; k++) acc += lats[k] * w1b[k * 1024 + jj];
        hc2cT[jj * 16 + b] = fmaxf(acc, 0.f);
    }
}

// ---- K2: p = hT^T @ w2 + b2  (streams w2; one column per thread, 16 batches)
__global__ __launch_bounds__(256) void k_hyper2(const float* __restrict__ hT,
        const float* __restrict__ w2, const float* __restrict__ b2v,
        float* __restrict__ outp, int K, int N) {
    extern __shared__ float hs[];     // [K][16]
    for (int i = threadIdx.x; i < K * 16; i += 256) hs[i] = hT[i];
    __syncthreads();
    int col = blockIdx.x * 256 + threadIdx.x;
    if (col >= N) return;
    float acc[16];
    float bias = b2v[col];
    #pragma unroll
    for (int b = 0; b < 16; b++) acc[b] = bias;
    #pragma unroll 4
    for (int k = 0; k < K; k++) {
        float wv = w2[(size_t)k * N + col];
        const f4v* h4 = (const f4v*)(hs + k * 16);
        f4v h0 = h4[0], h1 = h4[1], h2 = h4[2], h3 = h4[3];
        acc[0]  += h0[0] * wv; acc[1]  += h0[1] * wv; acc[2]  += h0[2] * wv; acc[3]  += h0[3] * wv;
        acc[4]  += h1[0] * wv; acc[5]  += h1[1] * wv; acc[6]  += h1[2] * wv; acc[7]  += h1[3] * wv;
        acc[8]  += h2[0] * wv; acc[9]  += h2[1] * wv; acc[10] += h2[2] * wv; acc[11] += h2[3] * wv;
        acc[12] += h3[0] * wv; acc[13] += h3[1] * wv; acc[14] += h3[2] * wv; acc[15] += h3[3] * wv;
    }
    #pragma unroll
    for (int b = 0; b < 16; b++) outp[(size_t)b * N + col] = acc[b];
}

// ---- K2b: pre-scale dynamic weights to bf16.
__global__ __launch_bounds__(256) void k_prepw(const float* __restrict__ pw, const float* __restrict__ pc,
        uint16_t* __restrict__ ww, uint16_t* __restrict__ wc) {
    int tid = blockIdx.x * 256 + threadIdx.x;
    const float s128 = 0.08838834764831845f;
    const float s64  = 0.125f;
    const float s2048 = 0.02209708691207961f;
    if (tid < 16 * 65536) {
        int b = tid >> 16, r = tid & 65535;
        ww[tid] = f2b(pw[(size_t)b * 65568 + r] * s2048);
    } else {
        int t = tid - 16 * 65536;
        int b = t / 24576, r = t % 24576;
        int src; float sc;
        if (r < 8192)       { src = r;                   sc = s128; }
        else if (r < 12288) { src = 8256  + (r - 8192);  sc = s64; }
        else if (r < 16384) { src = 12416 + (r - 12288); sc = s64; }
        else                { src = 16576 + (r - 16384); sc = s128; }
        wc[(size_t)b * 24576 + r] = f2b(pc[(size_t)b * 24832 + src] * sc);
    }
}

// ---- transpose + bf16-convert wave_bias [2048][16384] -> wbt [16384][2048]
__global__ __launch_bounds__(256) void k_transpose(const float* __restrict__ wb, uint16_t* __restrict__ wbt) {
    __shared__ uint16_t tile[64][66];
    int p0 = blockIdx.x * 64, i0 = blockIdx.y * 64;
    int lane = threadIdx.x & 63, grp = threadIdx.x >> 6;
    #pragma unroll
    for (int r = 0; r < 16; r++) {
        int i = grp * 16 + r;
        tile[i][lane] = f2b(wb[(size_t)(i0 + i) * 16384 + p0 + lane]);
    }
    __syncthreads();
    #pragma unroll
    for (int r = 0; r < 16; r++) {
        int p = grp * 16 + r;
        wbt[(size_t)(p0 + p) * 2048 + i0 + lane] = tile[lane][p];
    }
}

// ---- K3: wb[m=(b,o)][px] = sum_i ww[m][i]*wbt[px][i] + wbb[b][o]   M=512,N=16384,K=2048
__global__ __launch_bounds__(256) void k_wavegemm(const uint16_t* __restrict__ ww,
        const uint16_t* __restrict__ wbt, const float* __restrict__ pw, float* __restrict__ wb) {
    int id = blockIdx.x;                 // 0..511
    int xcd = id & 7, slot = id >> 3;    // slot 0..63 on this XCD
    int nt = xcd * 8 + (slot >> 3);      // 64 tiles of 256 px
    int mt = slot & 7;                   // 8 tiles of 64 rows
    int w = threadIdx.x >> 6, L = threadIdx.x & 63;
    int l15 = L & 15, quad = L >> 4;
    int pxbase = nt * 256 + w * 64;
    f4v acc[4][4];
    #pragma unroll
    for (int t = 0; t < 4; t++) {
        int m = mt * 64 + t * 16 + quad * 4;
        int b = m >> 5, o = m & 31;
        f4v bv = *(const f4v*)(pw + (size_t)b * 65568 + 65536 + o);
        #pragma unroll
        for (int j = 0; j < 4; j++) acc[t][j] = bv;
    }
    #pragma unroll 2
    for (int kk = 0; kk < 64; kk++) {
        s8v a[4], x[4];
        #pragma unroll
        for (int t = 0; t < 4; t++) {
            int m = mt * 64 + t * 16 + l15;
            a[t] = *(const s8v*)(ww + (size_t)m * 2048 + kk * 32 + quad * 8);
        }
        #pragma unroll
        for (int j = 0; j < 4; j++) {
            int p = pxbase + j * 16 + l15;
            x[j] = *(const s8v*)(wbt + (size_t)p * 2048 + kk * 32 + quad * 8);
        }
        #pragma unroll
        for (int t = 0; t < 4; t++)
            #pragma unroll
            for (int j = 0; j < 4; j++)
                acc[t][j] = __builtin_amdgcn_mfma_f32_16x16x32_bf16(a[t], x[j], acc[t][j], 0, 0, 0);
    }
    #pragma unroll
    for (int t = 0; t < 4; t++)
        #pragma unroll
        for (int j = 0; j < 4; j++)
            #pragma unroll
            for (int r = 0; r < 4; r++) {
                int row = mt * 64 + t * 16 + quad * 4 + r;
                int p = pxbase + j * 16 + l15;
                wb[(size_t)row * 16384 + p] = acc[t][j][r];
            }
}

// ---- K4a: per (b, channel c<32) inorm stats for BOTH cos (c) and sin (c+32),
// single pass over wb (var = E[x^2]-m^2).
__global__ __launch_bounds__(256) void k_wavestats(const float* __restrict__ wb, float* __restrict__ stats) {
    __shared__ float scratch[4];
    int c = blockIdx.x, b = blockIdx.y;          // c in 0..31
    const float* src = wb + (size_t)(b * 32 + c) * 16384;
    float sc = 0.f, sc2 = 0.f, ss = 0.f, ss2 = 0.f;
    for (int p = threadIdx.x; p < 16384; p += 256) {
        float x = src[p];
        float cv = __cosf(x), sv = __sinf(x);
        sc += cv; sc2 += cv * cv; ss += sv; ss2 += sv * sv;
    }
    float SC  = blockReduceSum(sc,  scratch);
    float SC2 = blockReduceSum(sc2, scratch);
    float SS  = blockReduceSum(ss,  scratch);
    float SS2 = blockReduceSum(ss2, scratch);
    if (threadIdx.x == 0) {
        float mc = SC * (1.f / 16384.f);
        float vc = fmaxf(SC2 * (1.f / 16384.f) - mc * mc, 0.f);
        float ms = SS * (1.f / 16384.f);
        float vs = fmaxf(SS2 * (1.f / 16384.f) - ms * ms, 0.f);
        stats[(b * 64 + c) * 2 + 0] = mc;
        stats[(b * 64 + c) * 2 + 1] = rsqrtf(vc + 1e-5f);
        stats[(b * 64 + 32 + c) * 2 + 0] = ms;
        stats[(b * 64 + 32 + c) * 2 + 1] = rsqrtf(vs + 1e-5f);
    }
}

// ---- K4b: write normalized wave into XIN[b][px][64+c] (pixel-major, bf16)
__global__ __launch_bounds__(256) void k_wavewrite(const float* __restrict__ wb,
        const float* __restrict__ stats, uint16_t* __restrict__ xin) {
    __shared__ uint16_t tl[256][66];
    __shared__ float sst[128];
    int b = blockIdx.y, p0 = blockIdx.x * 256;
    int t = threadIdx.x;
    if (t < 128) sst[t] = stats[b * 128 + t];
    __syncthreads();
    for (int c = 0; c < 32; c++) {
        int row = b * 32 + c;
        float x = wb[(size_t)row * 16384 + p0 + t];
        float cv = __cosf(x), sv = __sinf(x);
        tl[t][c]      = f2b((cv - sst[2 * c]) * sst[2 * c + 1]);
        tl[t][c + 32] = f2b((sv - sst[64 + 2 * c]) * sst[64 + 2 * c + 1]);
    }
    __syncthreads();
    uint16_t* dst = xin + ((size_t)(b * 16384 + p0 + t) * 128 + 64);
    const uint32_t* s32 = (const uint32_t*)&tl[t][0];
    #pragma unroll
    for (int c8 = 0; c8 < 64; c8 += 8) {
        uint4 v;
        v.x = s32[c8 / 2 + 0]; v.y = s32[c8 / 2 + 1];
        v.z = s32[c8 / 2 + 2]; v.w = s32[c8 / 2 + 3];
        *(uint4*)(dst + c8) = v;
    }
}

// ---- K5a: per-iteration sobel stats, float4-vectorized.
// block=(ic,b): channels 2ic (ky), 2ic+1 (kx). Each thread handles groups of
// 4 row-aligned pixels: 3 float4 loads + 2 edge scalars per group.
__global__ __launch_bounds__(256) void k_gstats(const float* __restrict__ prev, float* __restrict__ stats) {
    __shared__ float scratch[4];
    int ic = blockIdx.x, b = blockIdx.y;
    const float* src = prev + (size_t)(b * 32 + ic) * 16384;
    float sy = 0.f, sy2 = 0.f, sx = 0.f, sx2 = 0.f;
    const f4v zz = {0.f, 0.f, 0.f, 0.f};
    // 4096 groups of 4 px; group g covers p=4g..4g+3, all in row y=g>>5.
    for (int g = threadIdx.x; g < 4096; g += 256) {
        int p = g * 4;
        int y = g >> 5;
        int x0 = (g & 31) * 4;
        f4v up = (y > 0)   ? *(const f4v*)(src + p - 128) : zz;
        f4v dn = (y < 127) ? *(const f4v*)(src + p + 128) : zz;
        f4v c  = *(const f4v*)(src + p);
        float e0 = (x0 > 0)   ? src[p - 1] : 0.f;
        float e1 = (x0 < 124) ? src[p + 4] : 0.f;
        f4v vy = dn - up;
        f4v vx;
        vx[0] = c[1] - e0;
        vx[1] = c[2] - c[0];
        vx[2] = c[3] - c[1];
        vx[3] = e1   - c[2];
        #pragma unroll
        for (int i = 0; i < 4; i++) {
            sy += vy[i]; sy2 += vy[i] * vy[i];
            sx += vx[i]; sx2 += vx[i] * vx[i];
        }
    }
    float SY  = blockReduceSum(sy,  scratch);
    float SY2 = blockReduceSum(sy2, scratch);
    float SX  = blockReduceSum(sx,  scratch);
    float SX2 = blockReduceSum(sx2, scratch);
    if (threadIdx.x == 0) {
        float my = SY * (1.f / 16384.f);
        float vy = fmaxf(SY2 * (1.f / 16384.f) - my * my, 0.f);
        float mx = SX * (1.f / 16384.f);
        float vx = fmaxf(SX2 * (1.f / 16384.f) - mx * mx, 0.f);
        stats[(b * 64 + 2 * ic) * 2 + 0] = my;
        stats[(b * 64 + 2 * ic) * 2 + 1] = rsqrtf(vy + 1e-5f);
        stats[(b * 64 + 2 * ic + 1) * 2 + 0] = mx;
        stats[(b * 64 + 2 * ic + 1) * 2 + 1] = rsqrtf(vx + 1e-5f);
    }
}

// ---- K5b: write g = inorm(sobel(prev)) into XIN[b][px][0..64)
__global__ __launch_bounds__(256) void k_gwrite(const float* __restrict__ prev,
        const float* __restrict__ stats, uint16_t* __restrict__ xin) {
    __shared__ uint16_t tl[256][66];
    int b = blockIdx.y, p0 = blockIdx.x * 256;
    int t = threadIdx.x;
    int p = p0 + t;
    int y = p >> 7, x = p & 127;
    for (int ic = 0; ic < 32; ic++) {
        const float* src = prev + (size_t)(b * 32 + ic) * 16384;
        float up = (y > 0)   ? src[p - 128] : 0.f;
        float dn = (y < 127) ? src[p + 128] : 0.f;
        float lf = (x > 0)   ? src[p - 1]   : 0.f;
        float rt = (x < 127) ? src[p + 1]   : 0.f;
        int o = 2 * ic;
        float m0 = stats[(b * 64 + o) * 2], r0 = stats[(b * 64 + o) * 2 + 1];
        float m1 = stats[(b * 64 + o + 1) * 2], r1 = stats[(b * 64 + o + 1) * 2 + 1];
        tl[t][o]     = f2b((dn - up - m0) * r0);
        tl[t][o + 1] = f2b((rt - lf - m1) * r1);
    }
    __syncthreads();
    uint16_t* dst = xin + (size_t)(b * 16384 + p) * 128;
    const uint32_t* s32 = (const uint32_t*)&tl[t][0];
    #pragma unroll
    for (int c8 = 0; c8 < 64; c8 += 8) {
        uint4 v;
        v.x = s32[c8 / 2 + 0]; v.y = s32[c8 / 2 + 1];
        v.z = s32[c8 / 2 + 2]; v.w = s32[c8 / 2 + 3];
        *(uint4*)(dst + c8) = v;
    }
}

// ---- K6: fused conv chain, one scan step. Skip-GEMM fused into layer-1 so
// each X fragment is loaded once. State chained through embs slices.
__global__ __launch_bounds__(256) void k_conv(const uint16_t* __restrict__ wc,
        const uint16_t* __restrict__ xin, const float* __restrict__ pc,
        const float* __restrict__ prev, float* __restrict__ next,
        const float* __restrict__ leakp) {
    __shared__ uint16_t Hs[256][72];           // [px][ch]
    int b = blockIdx.y, p0 = blockIdx.x * 256;
    int w = threadIdx.x >> 6, L = threadIdx.x & 63;
    int l15 = L & 15, quad = L >> 4;
    const uint16_t* wcb = wc + (size_t)b * 24576;
    const float* pcb = pc + (size_t)b * 24832;
    size_t xbase = ((size_t)b * 16384 + p0 + w * 64) * 128;

    // ---- layer 1 + skip: acc1 = Win@X + b_in; acc3 = Wsk@X + (b_out+b_sk)
    f4v acc1[4][4], acc3[4][4];
    #pragma unroll
    for (int t = 0; t < 4; t++) {
        f4v bv1 = *(const f4v*)(pcb + 8192 + t * 16 + quad * 4);
        f4v bo  = *(const f4v*)(pcb + 16512 + t * 16 + quad * 4);
        f4v bs  = *(const f4v*)(pcb + 24768 + t * 16 + quad * 4);
        f4v bv3 = bo + bs;
        #pragma unroll
        for (int j = 0; j < 4; j++) { acc1[t][j] = bv1; acc3[t][j] = bv3; }
    }
    #pragma unroll
    for (int kk = 0; kk < 4; kk++) {
        s8v x[4];
        #pragma unroll
        for (int j = 0; j < 4; j++)
            x[j] = *(const s8v*)(xin + xbase + (size_t)(j * 16 + l15) * 128 + kk * 32 + quad * 8);
        #pragma unroll
        for (int t = 0; t < 4; t++) {
            s8v a1 = *(const s8v*)(wcb + (size_t)(t * 16 + l15) * 128 + kk * 32 + quad * 8);
            #pragma unroll
            for (int j = 0; j < 4; j++)
                acc1[t][j] = __builtin_amdgcn_mfma_f32_16x16x32_bf16(a1, x[j], acc1[t][j], 0, 0, 0);
        }
        #pragma unroll
        for (int t = 0; t < 4; t++) {
            s8v a3 = *(const s8v*)(wcb + 16384 + (size_t)(t * 16 + l15) * 128 + kk * 32 + quad * 8);
            #pragma unroll
            for (int j = 0; j < 4; j++)
                acc3[t][j] = __builtin_amdgcn_mfma_f32_16x16x32_bf16(a3, x[j], acc3[t][j], 0, 0, 0);
        }
    }
    #pragma unroll
    for (int t = 0; t < 4; t++)
        #pragma unroll
        for (int j = 0; j < 4; j++) {
            uint16_t pk[4];
            #pragma unroll
            for (int r = 0; r < 4; r++) {
                float v = acc1[t][j][r];
                pk[r] = f2b(v > 0.f ? v : 0.2f * v);
            }
            int px = w * 64 + j * 16 + l15;
            int ch = t * 16 + quad * 4;
            uint2 u; u.x = (uint32_t)pk[0] | ((uint32_t)pk[1] << 16);
            u.y = (uint32_t)pk[2] | ((uint32_t)pk[3] << 16);
            *(uint2*)&Hs[px][ch] = u;
        }
    __syncthreads();

    // ---- layer 2: H2 = lrelu(Wmid @ H1 + b_mid)
    f4v acc2[4][4];
    #pragma unroll
    for (int t = 0; t < 4; t++) {
        f4v bv = *(const f4v*)(pcb + 12352 + t * 16 + quad * 4);
        #pragma unroll
        for (int j = 0; j < 4; j++) acc2[t][j] = bv;
    }
    #pragma unroll
    for (int kk = 0; kk < 2; kk++) {
        s8v a[4], h[4];
        #pragma unroll
        for (int t = 0; t < 4; t++)
            a[t] = *(const s8v*)(wcb + 8192 + (size_t)(t * 16 + l15) * 64 + kk * 32 + quad * 8);
        #pragma unroll
        for (int j = 0; j < 4; j++) {
            int px = w * 64 + j * 16 + l15;
            h[j] = *(const s8v*)&Hs[px][kk * 32 + quad * 8];
        }
        #pragma unroll
        for (int t = 0; t < 4; t++)
            #pragma unroll
            for (int j = 0; j < 4; j++)
                acc2[t][j] = __builtin_amdgcn_mfma_f32_16x16x32_bf16(a[t], h[j], acc2[t][j], 0, 0, 0);
    }
    __syncthreads();
    #pragma unroll
    for (int t = 0; t < 4; t++)
        #pragma unroll
        for (int j = 0; j < 4; j++) {
            uint16_t pk[4];
            #pragma unroll
            for (int r = 0; r < 4; r++) {
                float v = acc2[t][j][r];
                pk[r] = f2b(v > 0.f ? v : 0.2f * v);
            }
            int px = w * 64 + j * 16 + l15;
            int ch = t * 16 + quad * 4;
            uint2 u; u.x = (uint32_t)pk[0] | ((uint32_t)pk[1] << 16);
            u.y = (uint32_t)pk[2] | ((uint32_t)pk[3] << 16);
            *(uint2*)&Hs[px][ch] = u;       // overwrite with H2
        }
    __syncthreads();

    // ---- layer 3 (mid part): acc3 += Wout @ H2
    #pragma unroll
    for (int kk = 0; kk < 2; kk++) {
        s8v a[4], h[4];
        #pragma unroll
        for (int t = 0; t < 4; t++)
            a[t] = *(const s8v*)(wcb + 12288 + (size_t)(t * 16 + l15) * 64 + kk * 32 + quad * 8);
        #pragma unroll
        for (int j = 0; j < 4; j++) {
            int px = w * 64 + j * 16 + l15;
            h[j] = *(const s8v*)&Hs[px][kk * 32 + quad * 8];
        }
        #pragma unroll
        for (int t = 0; t < 4; t++)
            #pragma unroll
            for (int j = 0; j < 4; j++)
                acc3[t][j] = __builtin_amdgcn_mfma_f32_16x16x32_bf16(a[t], h[j], acc3[t][j], 0, 0, 0);
    }

    // ---- epilogue: GLU gate + leaky integrate into NEXT embs slice.
    float leak = leakp[0];
    leak = fminf(fmaxf(leak, 0.001f), 1000.f);
    #pragma unroll
    for (int t = 0; t < 2; t++)
        #pragma unroll
        for (int j = 0; j < 4; j++) {
            int px = p0 + w * 64 + j * 16 + l15;
            #pragma unroll
            for (int r = 0; r < 4; r++) {
                int ch = t * 16 + quad * 4 + r;
                float y1 = acc3[t][j][r];
                float y2 = acc3[t + 2][j][r];
                float on = y1 / (1.f + __expf(-y2));
                size_t idx = (size_t)(b * 32 + ch) * 16384 + px;
                next[idx] = prev[idx] + leak * on;
            }
        }
}

// ---- K7: out_raw = out @ out_w^T + out_b; clip -> d_out[0], raw -> d_out[2]
__global__ __launch_bounds__(256) void k_final(const float* __restrict__ outs,
        const float* __restrict__ ow, const float* __restrict__ ob,
        float* __restrict__ dclip, float* __restrict__ draw) {
    __shared__ float ws[3][32];
    __shared__ float obs[3];
    int b = blockIdx.y, p0 = blockIdx.x * 256;
    int t = threadIdx.x;
    if (t < 96) ws[t / 32][t % 32] = ow[t];
    if (t < 3) obs[t] = ob[t];
    __syncthreads();
    int p = p0 + t;
    float a0 = obs[0], a1 = obs[1], a2 = obs[2];
    #pragma unroll 4
    for (int c = 0; c < 32; c++) {
        float v = outs[(size_t)(b * 32 + c) * 16384 + p];
        a0 += v * ws[0][c]; a1 += v * ws[1][c]; a2 += v * ws[2][c];
    }
    float raw[3] = {a0, a1, a2};
    #pragma unroll
    for (int oc = 0; oc < 3; oc++) {
        size_t idx = (size_t)(b * 3 + oc) * 16384 + p;
        draw[idx] = raw[oc];
        dclip[idx] = fminf(fmaxf(raw[oc], -1.f), 1.f);
    }
}

// ---------------------------------------------------------------------------
extern "C" void kernel_launch(void* const* d_in, const int* in_sizes, int n_in,
                              void* d_out, int out_size, void* d_ws, size_t ws_size,
                              hipStream_t stream) {
    const float* lat   = (const float*)d_in[0];
    const float* leakp = (const float*)d_in[1];
    const float* wbias = (const float*)d_in[2];
    const float* wtw1  = (const float*)d_in[3];
    const float* wtb1  = (const float*)d_in[4];
    const float* wtw2  = (const float*)d_in[5];
    const float* wtb2  = (const float*)d_in[6];
    const float* cw1   = (const float*)d_in[7];
    const float* cb1   = (const float*)d_in[8];
    const float* cw2   = (const float*)d_in[9];
    const float* cb2   = (const float*)d_in[10];
    const float* outw  = (const float*)d_in[11];
    const float* outb  = (const float*)d_in[12];
    float* out_f = (float*)d_out;

    char* ws = (char*)d_ws;
    float*    hwtT  = (float*)(ws + 0);            //  32768 B
    float*    hc2cT = (float*)(ws + 32768);        //  65536 B
    float*    pw    = (float*)(ws + 98304);        //  16x65568 f32
    float*    pc    = (float*)(ws + 4294656);      //  16x24832 f32
    uint16_t* ww    = (uint16_t*)(ws + 5883904);   //  512x2048 bf16
    uint16_t* wc    = (uint16_t*)(ws + 7981056);   //  16x24576 bf16
    float*    statw = (float*)(ws + 8767488);      //  16x64x2 f32
    float*    statg = (float*)(ws + 8775680);      //  16x64x2 f32
    float*    wb    = (float*)(ws + 8783872);      //  512x16384 f32
    uint16_t* wbt   = (uint16_t*)(ws + 42338304);  //  16384x2048 bf16
    uint16_t* xin   = (uint16_t*)(ws + 109447168); //  16x16384x128 bf16

    float* emb0 = out_f + 786432;                  // embs[0] slice (= scan state 0)

    hipMemsetAsync(emb0, 0, 33554432, stream);     // embs[0] = out0 = 0
    hipMemsetAsync(statg, 0, 8192, stream);        // it=0 stats (sobel of 0 is 0)

    k_hyper1<<<dim3(6, 16), 256, 0, stream>>>(lat, wtw1, wtb1, cw1, cb1, hwtT, hc2cT);
    k_hyper2<<<dim3(257), 256, 32768, stream>>>(hwtT, wtw2, wtb2, pw, 512, 65568);
    k_hyper2<<<dim3(97), 256, 65536, stream>>>(hc2cT, cw2, cb2, pc, 1024, 24832);
    k_prepw<<<dim3(5632), 256, 0, stream>>>(pw, pc, ww, wc);
    k_transpose<<<dim3(256, 32), 256, 0, stream>>>(wbias, wbt);
    k_wavegemm<<<dim3(512), 256, 0, stream>>>(ww, wbt, pw, wb);
    k_wavestats<<<dim3(32, 16), 256, 0, stream>>>(wb, statw);
    k_wavewrite<<<dim3(64, 16), 256, 0, stream>>>(wb, statw, xin);

    for (int it = 0; it < 12; ++it) {
        const float* prev = emb0 + (size_t)it * 8388608;
        float* next = emb0 + (size_t)(it + 1) * 8388608;
        if (it > 0)
            k_gstats<<<dim3(32, 16), 256, 0, stream>>>(prev, statg);
        k_gwrite<<<dim3(64, 16), 256, 0, stream>>>(prev, statg, xin);
        k_conv<<<dim3(64, 16), 256, 0, stream>>>(wc, xin, pc, prev, next, leakp);
    }
    k_final<<<dim3(64, 16), 256, 0, stream>>>(emb0 + (size_t)12 * 8388608, outw, outb,
                                              out_f, out_f + 109838336);
}